// Round 1
// 17756.650 us; speedup vs baseline: 2.1379x; 2.1379x over previous
//
#include <hip/hip_runtime.h>
#include <math.h>

#define NB   32      // batch (= GEMM M)
#define NPF  100
#define FIN  36
#define FC   40
#define KSEL 11
#define HH   3600
#define EPSB 0.001
#define ETA_C 12
#define PHI_C 13
#define MROWS 32
#define PSTRIDE (MROWS * HH)   // one split-K partial slot: 115200 doubles
#define SKH  17                // hidden split-K (grid 15x17 = 255 blocks ~ 1/CU)
#define KRCH 212               // 17*212 = 3604 >= 3600
#define SK0  16                // L0 split-K
#define KRC0 28                // 16*28 = 448 >= 440
#define NFIXB 450              // fix grid (450*8 = 3600)

// ---------------------------------------------------------------------------
// Preprocess (f64): embeddings + normalization -> x[32][100][40]
// ---------------------------------------------------------------------------
__global__ __launch_bounds__(256) void pre_kernel(
    const float* __restrict__ xx, const float* __restrict__ emb1,
    const float* __restrict__ emb2, const float* __restrict__ emb3,
    const float* __restrict__ mean, const float* __restrict__ std_,
    const float* __restrict__ vmin, const float* __restrict__ vmax,
    double* __restrict__ x)
{
    int b = blockIdx.x;
    for (int t = threadIdx.x; t < NPF * FC; t += 256) {
        int p = t / FC, c = t % FC;
        const float* row = xx + (size_t)(b * NPF + p) * FIN;
        double v;
        if (c < 2) {
            int idx = (int)fabsf(row[0]);
            v = (double)emb1[2 * idx + c];
        } else if (c < 4) {
            int idx = (int)fabsf(row[1]);
            v = (double)emb2[2 * idx + (c - 2)];
        } else if (c < 6) {
            int idx = (int)fabsf(row[2]);
            v = (double)emb3[2 * idx + (c - 4)];
        } else {
            int f = c - 4;                  // c=6 -> feature 2
            v = (double)row[f];
            if (f >= 3) {
                double y = fmin(fmax((v - (double)mean[f]) / (double)std_[f], -5.0), 5.0);
                double sc = 2.0 / ((double)vmax[f] - (double)vmin[f]);
                v = fmin(fmax(sc * (y - (double)vmin[f]) - 1.0, -1.0), 1.0);
            }
        }
        x[(size_t)(b * NPF + p) * FC + c] = v;
    }
}

// ---------------------------------------------------------------------------
// GEMM (f64): P[slot by][32][3600] = A[k0:kend][32]^T-slice @ W[k][3600]
// A is k-major [KA][32] so a k-column is wave-uniform -> scalar loads.
// v2: 512 threads = 8 waves = 4 rowgroups x 8 rows; each thread 8 rows x 2
// contiguous cols (acc 8x2 f64 = 32 VGPR). 2 waves/SIMD at 255 blocks ->
// one wave's L3 W-load latency hides under the other's 16 FMAs; the 4
// rowgroups re-read the same W float2s (L1 hits). unroll 4 for lookahead.
// ---------------------------------------------------------------------------
__global__ __launch_bounds__(512) void gemm_kernel(
    const double* __restrict__ A, const float* __restrict__ W,
    double* __restrict__ P, int KA, int KRC)
{
    const int tid = threadIdx.x;
    const int rg = __builtin_amdgcn_readfirstlane(tid >> 7);  // wave-uniform rowgroup 0..3
    const int lh = tid & 127;
    const int j0 = blockIdx.x * 256 + lh * 2;
    const bool jok = (j0 < HH);
    const int jc = jok ? j0 : (HH - 2);     // clamp for tail-block loads
    const int k0 = blockIdx.y * KRC;
    const int kend = min(k0 + KRC, KA);

    double acc[8][2];
#pragma unroll
    for (int r = 0; r < 8; ++r) { acc[r][0] = 0.0; acc[r][1] = 0.0; }

    const double* __restrict__ Ap = A + (size_t)k0 * MROWS + rg * 8;
    const float* __restrict__ Wp = W + (size_t)k0 * HH + jc;

#pragma unroll 4
    for (int k = k0; k < kend; ++k) {
        float2 wv = *(const float2*)Wp;
        double w0 = (double)wv.x, w1 = (double)wv.y;
#pragma unroll
        for (int r = 0; r < 8; ++r) {
            double a = Ap[r];               // uniform address -> s_load
            acc[r][0] = fma(a, w0, acc[r][0]);
            acc[r][1] = fma(a, w1, acc[r][1]);
        }
        Ap += MROWS;
        Wp += HH;
    }
    if (jok) {
        double* op = P + (size_t)blockIdx.y * PSTRIDE + (size_t)(rg * 8) * HH + j0;
#pragma unroll
        for (int r = 0; r < 8; ++r)
            *(double2*)(op + (size_t)r * HH) = make_double2(acc[r][0], acc[r][1]);
    }
}

// ---------------------------------------------------------------------------
// Fixup: sum nslot partial slots + bias + BN + ReLU -> Aout[k=out-col][32 rows]
// (transposed k-major layout for the next GEMM's scalar loads).
// Block 256 = 32 rows x 8 cols; grid 450 (450*8 = 3600).
// do_c2: additionally emit per-block partial c2 = act^T @ Wc contributions
// (8-lane shfl reduce over jj) so the serial knn kernel only sums 450
// partials instead of a scattered 3600-element dot.
// ---------------------------------------------------------------------------
__global__ __launch_bounds__(256) void fix_kernel(
    const double* __restrict__ P, int nslot,
    const float* __restrict__ bias, const float* __restrict__ gam,
    const float* __restrict__ bet, const float* __restrict__ mm,
    const float* __restrict__ mv, double* __restrict__ Aout,
    const float* __restrict__ Wc, double* __restrict__ c2part, int do_c2)
{
    __shared__ double t[8][33];
    const int tid = threadIdx.x;
    const int r = tid >> 3, jj = tid & 7;   // r = batch row, jj = col-in-block
    const int j = blockIdx.x * 8 + jj;
    const double* p = P + (size_t)r * HH + j;
    double s = 0.0;
    for (int sl = 0; sl < nslot; ++sl) s += p[(size_t)sl * PSTRIDE];
    s += (double)bias[j];
    s = (double)gam[j] * (s - (double)mm[j]) * (1.0 / sqrt((double)mv[j] + EPSB))
      + (double)bet[j];
    s = fmax(s, 0.0);
    t[jj][r] = s;
    if (do_c2) {
        double pc0 = s * (double)Wc[2 * j];
        double pc1 = s * (double)Wc[2 * j + 1];
        // lanes of a wave = 8 batch-rows x 8 jj (jj in low 3 bits) -> xor-reduce jj
        pc0 += __shfl_xor(pc0, 1); pc1 += __shfl_xor(pc1, 1);
        pc0 += __shfl_xor(pc0, 2); pc1 += __shfl_xor(pc1, 2);
        pc0 += __shfl_xor(pc0, 4); pc1 += __shfl_xor(pc1, 4);
        if (jj == 0) {
            c2part[(size_t)blockIdx.x * 64 + r * 2]     = pc0;
            c2part[(size_t)blockIdx.x * 64 + r * 2 + 1] = pc1;
        }
    }
    __syncthreads();
    const int jj2 = tid >> 5, r2 = tid & 31;
    Aout[(size_t)(blockIdx.x * 8 + jj2) * MROWS + r2] = t[jj2][r2];
}

// ---------------------------------------------------------------------------
// KNN (f64): c2 = sum of fix-produced partials + bc, distances,
// stable top-11, gather g^T [440][32] (k-major for L0 scalar loads)
// ---------------------------------------------------------------------------
__global__ __launch_bounds__(256) void knn_kernel(
    const double* __restrict__ x, const double* __restrict__ c2part,
    const float* __restrict__ bc,
    double* __restrict__ g_out, int first)
{
    int b = blockIdx.x, tid = threadIdx.x;
    __shared__ double sd[NPF];
    __shared__ int    sel[KSEL];
    __shared__ double sc2[2];
    __shared__ double red[8];

    double c2x, c2y;
    if (first) {
        c2x = x[(size_t)(b * NPF) * FC + ETA_C];
        c2y = x[(size_t)(b * NPF) * FC + PHI_C];
    } else {
        double ax = 0.0, ay = 0.0;
        for (int blk = tid; blk < NFIXB; blk += 256) {
            ax += c2part[(size_t)blk * 64 + b * 2];
            ay += c2part[(size_t)blk * 64 + b * 2 + 1];
        }
        for (int o = 32; o >= 1; o >>= 1) {
            ax += __shfl_xor(ax, o);
            ay += __shfl_xor(ay, o);
        }
        int wv = tid >> 6;
        if ((tid & 63) == 0) { red[wv * 2] = ax; red[wv * 2 + 1] = ay; }
        __syncthreads();
        if (tid == 0) {
            sc2[0] = red[0] + red[2] + red[4] + red[6] + (double)bc[0];
            sc2[1] = red[1] + red[3] + red[5] + red[7] + (double)bc[1];
        }
        __syncthreads();
        c2x = sc2[0]; c2y = sc2[1];
    }
    if (tid < NPF) {
        double dx = x[(size_t)(b * NPF + tid) * FC + ETA_C] - c2x;
        double dy = x[(size_t)(b * NPF + tid) * FC + PHI_C] - c2y;
        sd[tid] = sqrt(dx * dx + dy * dy);
    }
    __syncthreads();
    if (tid < NPF) {
        double dp = sd[tid];
        int cnt = 0;
        for (int q = 0; q < NPF; ++q) {
            double dq = sd[q];
            cnt += (dq < dp) || (dq == dp && q < tid);  // stable top-k order
        }
        if (cnt < KSEL) sel[cnt] = tid;
    }
    __syncthreads();
    for (int t = tid; t < KSEL * FC; t += 256) {
        int kk = t / FC, f = t % FC;
        g_out[(size_t)t * MROWS + b] = x[(size_t)(b * NPF + sel[kk]) * FC + f];
    }
}

// ---------------------------------------------------------------------------
// Head (f64): act (pre-activated) -> x2, softmax, weighted sums -> out[32][6]
// ---------------------------------------------------------------------------
__global__ __launch_bounds__(256) void head_kernel(
    const float* __restrict__ xx, const double* __restrict__ act,
    const float* __restrict__ W2, const float* __restrict__ b2,
    const float* __restrict__ W100, const float* __restrict__ b100,
    float* __restrict__ out)
{
    int b = blockIdx.x, tid = threadIdx.x;
    __shared__ double hs[HH];
    __shared__ double buf[NPF];
    __shared__ double red[8];
    __shared__ double acc4[4 * NPF];
    __shared__ double sstat[2];

    for (int j = tid; j < HH; j += 256) hs[j] = act[(size_t)j * MROWS + b];
    __syncthreads();
    double a0 = 0.0, a1 = 0.0;
    for (int j = tid; j < HH; j += 256) {
        a0 += hs[j] * (double)W2[2 * j];
        a1 += hs[j] * (double)W2[2 * j + 1];
    }
    for (int o = 32; o >= 1; o >>= 1) { a0 += __shfl_xor(a0, o); a1 += __shfl_xor(a1, o); }
    if ((tid & 63) == 0) { red[(tid >> 6) * 2] = a0; red[(tid >> 6) * 2 + 1] = a1; }
    double lg = 0.0;
    int p = tid >> 1, half = tid & 1;
    if (tid < 2 * NPF) {
        for (int j = half * (HH / 2); j < (half + 1) * (HH / 2); ++j)
            lg += hs[j] * (double)W100[(size_t)j * NPF + p];
    }
    lg += __shfl_xor(lg, 1);
    __syncthreads();
    if (tid < 2 * NPF && half == 0) buf[p] = lg + (double)b100[p];
    __syncthreads();
    if (tid == 0) {
        double m = buf[0];
        for (int q = 1; q < NPF; ++q) m = fmax(m, buf[q]);
        sstat[0] = m;
    }
    __syncthreads();
    if (tid < NPF) buf[tid] = exp(buf[tid] - sstat[0]);
    __syncthreads();
    if (tid == 0) {
        double sm = 0.0;
        for (int q = 0; q < NPF; ++q) sm += buf[q];
        sstat[1] = sm;
    }
    __syncthreads();
    if (tid < NPF) {
        const float* row = xx + (size_t)(b * NPF + tid) * FIN;
        double w = buf[tid] / sstat[1] * (double)row[7];
        acc4[tid]           = (double)row[3] * w;
        acc4[NPF + tid]     = (double)row[4] * w;
        acc4[2 * NPF + tid] = (double)row[5] * w;
        acc4[3 * NPF + tid] = (double)row[6] * w;
    }
    __syncthreads();
    if (tid == 0) {
        double px = 0.0, py = 0.0, pz = 0.0, E = 0.0;
        for (int q = 0; q < NPF; ++q) {
            px += acc4[q]; py += acc4[NPF + q]; pz += acc4[2 * NPF + q]; E += acc4[3 * NPF + q];
        }
        double x2_0 = red[0] + red[2] + red[4] + red[6] + (double)b2[0];
        double x2_1 = red[1] + red[3] + red[5] + red[7] + (double)b2[1];
        double px2 = px * px, py2 = py * py, pz2 = pz * pz;
        double pt = sqrt(px2 + py2);
        double mass2 = E * E - px2 - py2 - pz2;
        double absp = sqrt(px2 + py2 + pz2);
        double cosT = (absp == 0.0) ? 1.0 : pz / absp;
        bool ok = cosT * cosT < 1.0;
        double ratio = ok ? (1.0 - cosT) / (1.0 + cosT) : 1.0;
        double eta = ok ? -0.5 * log(ratio) : 0.0;
        double phi = (px == 0.0 && py == 0.0) ? 0.0 : atan2(py, px);
        out[b * 6 + 0] = (float)x2_0; out[b * 6 + 1] = (float)x2_1; out[b * 6 + 2] = (float)pt;
        out[b * 6 + 3] = (float)eta;  out[b * 6 + 4] = (float)phi;  out[b * 6 + 5] = (float)mass2;
    }
}

// ---------------------------------------------------------------------------
extern "C" void kernel_launch(void* const* d_in, const int* in_sizes, int n_in,
                              void* d_out, int out_size, void* d_ws, size_t ws_size,
                              hipStream_t stream)
{
    const float* xx    = (const float*)d_in[0];
    const float* emb1  = (const float*)d_in[1];
    const float* emb2  = (const float*)d_in[2];
    const float* emb3  = (const float*)d_in[3];
    const float* mean  = (const float*)d_in[4];
    const float* std_  = (const float*)d_in[5];
    const float* vmin  = (const float*)d_in[6];
    const float* vmax  = (const float*)d_in[7];
    const float* W0    = (const float*)d_in[8];
    const float* b0    = (const float*)d_in[9];
    const float* Wh    = (const float*)d_in[10];
    const float* bh    = (const float*)d_in[11];
    const float* gamma = (const float*)d_in[12];
    const float* beta  = (const float*)d_in[13];
    const float* mmean = (const float*)d_in[14];
    const float* mvar  = (const float*)d_in[15];
    const float* Wc    = (const float*)d_in[16];
    const float* bc    = (const float*)d_in[17];
    const float* W2    = (const float*)d_in[18];
    const float* b2    = (const float*)d_in[19];
    const float* W100  = (const float*)d_in[20];
    const float* b100  = (const float*)d_in[21];

    double* ws   = (double*)d_ws;
    double* x    = ws;                        // 128000
    double* gbuf = x + NB * NPF * FC;         // 440*32 = 14080 (k-major)
    double* Aa   = gbuf + 440 * MROWS;        // 115200 (k-major activations)
    double* Ab   = Aa + PSTRIDE;              // 115200
    double* act  = Ab + PSTRIDE;              // 115200
    double* P    = act + PSTRIDE;             // 17*115200 partial slots (~19.6 MB total)
    // c2part[450][32][2] aliases the head of Ab: Ab is dead between the L4
    // gemm's last read and the L1 fix's rewrite; c2part is written by the L4
    // fix and consumed by the next knn, strictly inside that window.
    double* c2part = Ab;                      // 450*64 = 28800 doubles

    const size_t HS = (size_t)HH;

    pre_kernel<<<dim3(NB), dim3(256), 0, stream>>>(xx, emb1, emb2, emb3, mean, std_, vmin, vmax, x);

    for (int t = 0; t < NPF; ++t) {
        knn_kernel<<<dim3(NB), dim3(256), 0, stream>>>(x, c2part, bc, gbuf, (t == 0) ? 1 : 0);
        // L0: g^T[440][32] @ W0 -> P[0..15]
        gemm_kernel<<<dim3(15, SK0), dim3(512), 0, stream>>>(gbuf, W0, P, 440, KRC0);
        fix_kernel<<<dim3(NFIXB), dim3(256), 0, stream>>>(P, SK0, b0, gamma, beta, mmean, mvar, Aa,
                                                          nullptr, nullptr, 0);
        // L1..L4
        gemm_kernel<<<dim3(15, SKH), dim3(512), 0, stream>>>(Aa, Wh, P, HH, KRCH);
        fix_kernel<<<dim3(NFIXB), dim3(256), 0, stream>>>(P, SKH, bh, gamma + HS, beta + HS,
                                                          mmean + HS, mvar + HS, Ab,
                                                          nullptr, nullptr, 0);
        gemm_kernel<<<dim3(15, SKH), dim3(512), 0, stream>>>(Ab, Wh + HS * HS, P, HH, KRCH);
        fix_kernel<<<dim3(NFIXB), dim3(256), 0, stream>>>(P, SKH, bh + HS, gamma + 2 * HS, beta + 2 * HS,
                                                          mmean + 2 * HS, mvar + 2 * HS, Aa,
                                                          nullptr, nullptr, 0);
        gemm_kernel<<<dim3(15, SKH), dim3(512), 0, stream>>>(Aa, Wh + 2 * HS * HS, P, HH, KRCH);
        fix_kernel<<<dim3(NFIXB), dim3(256), 0, stream>>>(P, SKH, bh + 2 * HS, gamma + 3 * HS, beta + 3 * HS,
                                                          mmean + 3 * HS, mvar + 3 * HS, Ab,
                                                          nullptr, nullptr, 0);
        gemm_kernel<<<dim3(15, SKH), dim3(512), 0, stream>>>(Ab, Wh + 3 * HS * HS, P, HH, KRCH);
        fix_kernel<<<dim3(NFIXB), dim3(256), 0, stream>>>(P, SKH, bh + 3 * HS, gamma + 4 * HS, beta + 4 * HS,
                                                          mmean + 4 * HS, mvar + 4 * HS, act,
                                                          Wc, c2part, 1);
    }
    head_kernel<<<dim3(NB), dim3(256), 0, stream>>>(xx, act, W2, b2, W100, b100, (float*)d_out);
}